// Round 2
// baseline (196.410 us; speedup 1.0000x reference)
//
#include <hip/hip_runtime.h>
#include <math.h>

#define D 128
#define C 64
#define P1_THREADS 256
#define P1_GRID 512

// Monotone float->uint key: preserves order under unsigned max.
// key(x) >= key(-inf) = 0x007FFFFF > 0 for any real x, so 0 == "empty".
__device__ __forceinline__ unsigned f2key(float f) {
  unsigned u = __float_as_uint(f);
  return (u & 0x80000000u) ? ~u : (u | 0x80000000u);
}
__device__ __forceinline__ float key2f(unsigned k) {
  unsigned u = (k & 0x80000000u) ? (k & 0x7fffffffu) : ~k;
  return __uint_as_float(u);
}

// Phase 1: per-block segment max via fire-and-forget LDS atomicMax (ds_max_u32,
// no return -> no read-modify-write latency chain). float4 loads: 32 lanes/row.
// LDS layout transposed-swizzled: idx = core*128 + (d%4)*32 + d/4, so the 4
// ds_max ops per thread hit banks {lane} -> 2-way per wave (free).
__global__ __launch_bounds__(P1_THREADS) void p1_segmax(
    const int* __restrict__ assign, const float* __restrict__ qe,
    unsigned* __restrict__ part, int Q, int niter) {
  __shared__ unsigned buf[C * D];  // 32 KB
  int tid = threadIdx.x;
  for (int i = tid; i < C * D; i += P1_THREADS) buf[i] = 0u;
  __syncthreads();

  int lane = tid & 31;   // dim quad: dims [lane*4, lane*4+4)
  int r = tid >> 5;      // row slot 0..7

  for (int it = blockIdx.x; it < niter; it += gridDim.x) {
    int base = it * 16;
    int r0 = base + r;
    int r1 = base + 8 + r;
    if (r1 < Q) {
      float4 v0 = *(const float4*)&qe[(size_t)r0 * D + lane * 4];
      float4 v1 = *(const float4*)&qe[(size_t)r1 * D + lane * 4];
      int a0 = assign[r0] * D + lane;
      int a1 = assign[r1] * D + lane;
      atomicMax(&buf[a0 +  0], f2key(v0.x));
      atomicMax(&buf[a0 + 32], f2key(v0.y));
      atomicMax(&buf[a0 + 64], f2key(v0.z));
      atomicMax(&buf[a0 + 96], f2key(v0.w));
      atomicMax(&buf[a1 +  0], f2key(v1.x));
      atomicMax(&buf[a1 + 32], f2key(v1.y));
      atomicMax(&buf[a1 + 64], f2key(v1.z));
      atomicMax(&buf[a1 + 96], f2key(v1.w));
    } else {
      for (int rr = r0; rr <= base + 15; rr += 8) {
        if (rr < Q) {
          float4 v = *(const float4*)&qe[(size_t)rr * D + lane * 4];
          int a = assign[rr] * D + lane;
          atomicMax(&buf[a +  0], f2key(v.x));
          atomicMax(&buf[a + 32], f2key(v.y));
          atomicMax(&buf[a + 64], f2key(v.z));
          atomicMax(&buf[a + 96], f2key(v.w));
        }
      }
    }
  }
  __syncthreads();

  // Un-swizzle on write-out (once per block; 4-way LDS conflict here is noise).
  unsigned* outp = part + (size_t)blockIdx.x * (C * D);
  for (int i = tid; i < C * D; i += P1_THREADS) {
    int c = i >> 7, d = i & 127;
    outp[i] = buf[c * D + (d & 3) * 32 + (d >> 2)];
  }
}

// Phase 2: reduce nb partial key-buffers -> core_embs (float, padding applied).
// Block = 16 outputs x 16 readers.
__global__ __launch_bounds__(256) void p2_merge(
    const unsigned* __restrict__ part, const float* __restrict__ padding,
    float* __restrict__ core_embs, int nb) {
  __shared__ unsigned red[256];
  int tid = threadIdx.x;
  int o_local = tid & 15;
  int rdr = tid >> 4;
  int o = blockIdx.x * 16 + o_local;
  unsigned m = 0u;
  for (int br = rdr; br < nb; br += 16)
    m = max(m, part[(size_t)br * (C * D) + o]);
  red[tid] = m;
  __syncthreads();
  for (int s = 8; s >= 1; s >>= 1) {
    if (rdr < s)
      red[rdr * 16 + o_local] = max(red[rdr * 16 + o_local], red[(rdr + s) * 16 + o_local]);
    __syncthreads();
  }
  if (rdr == 0) {
    unsigned k = red[o_local];
    core_embs[o] = k ? key2f(k) : padding[o & (D - 1)];
  }
}

// Phase 3a: tmp = core_embs @ W_msg   [C,D] x [D,D]
__global__ __launch_bounds__(D) void p3a_gemm(
    const float* __restrict__ core_embs, const float* __restrict__ Wmsg,
    float* __restrict__ tmp) {
  __shared__ float xrow[D];
  int t = threadIdx.x;
  int j = blockIdx.x;
  xrow[t] = core_embs[j * D + t];
  __syncthreads();
  float acc = 0.f;
#pragma unroll 8
  for (int k = 0; k < D; ++k) acc += xrow[k] * Wmsg[k * D + t];
  tmp[j * D + t] = acc;
}

// Phase 3b: out = relu(core_embs @ W_self + core_con @ tmp + b)
__global__ __launch_bounds__(D) void p3b_out(
    const float* __restrict__ core_embs, const float* __restrict__ con,
    const float* __restrict__ tmp, const float* __restrict__ Wself,
    const float* __restrict__ b, float* __restrict__ out) {
  __shared__ float ce[D];
  __shared__ float cr[C];
  int t = threadIdx.x;
  int c = blockIdx.x;
  ce[t] = core_embs[c * D + t];
  if (t < C) cr[t] = con[c * C + t];
  __syncthreads();
  float acc = b[t];
#pragma unroll 8
  for (int k = 0; k < D; ++k) acc += ce[k] * Wself[k * D + t];
#pragma unroll 8
  for (int j = 0; j < C; ++j) acc += cr[j] * tmp[j * D + t];
  out[c * D + t] = fmaxf(acc, 0.f);
}

extern "C" void kernel_launch(void* const* d_in, const int* in_sizes, int n_in,
                              void* d_out, int out_size, void* d_ws, size_t ws_size,
                              hipStream_t stream) {
  const int* assign    = (const int*)d_in[0];
  const float* qe      = (const float*)d_in[1];
  const float* padding = (const float*)d_in[2];
  const float* con     = (const float*)d_in[3];
  const float* Wself   = (const float*)d_in[4];
  const float* Wmsg    = (const float*)d_in[5];
  const float* b       = (const float*)d_in[6];
  float* out = (float*)d_out;
  int Q = in_sizes[0];

  const size_t slot = (size_t)C * D;  // 8192 elems = 32 KB
  size_t avail = ws_size / 4;
  long nb_max = (long)((avail > 2 * slot ? avail - 2 * slot : slot) / slot);
  int nb = (int)(nb_max < P1_GRID ? nb_max : P1_GRID);
  if (nb < 1) nb = 1;

  unsigned* part   = (unsigned*)d_ws;
  float* core_embs = (float*)((unsigned*)d_ws + (size_t)nb * slot);
  float* tmp       = core_embs + slot;

  int niter = (Q + 15) / 16;

  hipLaunchKernelGGL(p1_segmax, dim3(nb), dim3(P1_THREADS), 0, stream,
                     assign, qe, part, Q, niter);
  hipLaunchKernelGGL(p2_merge, dim3((C * D) / 16), dim3(256), 0, stream,
                     part, padding, core_embs, nb);
  hipLaunchKernelGGL(p3a_gemm, dim3(C), dim3(D), 0, stream,
                     core_embs, Wmsg, tmp);
  hipLaunchKernelGGL(p3b_out, dim3(C), dim3(D), 0, stream,
                     core_embs, con, tmp, Wself, b, out);
}

// Round 3
// 187.214 us; speedup vs baseline: 1.0491x; 1.0491x over previous
//
#include <hip/hip_runtime.h>
#include <math.h>

#define D 128
#define C 64
#define P1_THREADS 256
#define P1_GRID 512   // = nb partial buffers; 2 blocks/CU (32 KB LDS each)

// Monotone float->uint key: preserves order under unsigned max.
// key(x) >= key(-inf) > 0 for any real x, so 0 == "empty".
__device__ __forceinline__ unsigned f2key(float f) {
  unsigned u = __float_as_uint(f);
  return (u & 0x80000000u) ? ~u : (u | 0x80000000u);
}
__device__ __forceinline__ float key2f(unsigned k) {
  unsigned u = (k & 0x80000000u) ? (k & 0x7fffffffu) : ~k;
  return __uint_as_float(u);
}

// Phase 1: per-block segment max via fire-and-forget LDS atomicMax (ds_max_u32,
// no return -> no RMW latency chain). Tile = 32 rows; each thread handles 4
// rows -> 4 float4 loads in flight per thread for latency hiding.
// LDS swizzle: idx = core*128 + (d%4)*32 + d/4 -> each ds_max wave-op is
// 2-way per bank (free, m136).
__global__ __launch_bounds__(P1_THREADS) void p1_segmax(
    const int* __restrict__ assign, const float* __restrict__ qe,
    unsigned* __restrict__ part, int Q, int niter) {
  __shared__ unsigned buf[C * D];  // 32 KB
  int tid = threadIdx.x;
  for (int i = tid; i < C * D; i += P1_THREADS) buf[i] = 0u;
  __syncthreads();

  int lane = tid & 31;  // dim quad: dims [lane*4, lane*4+4)
  int r = tid >> 5;     // row slot 0..7

  for (int it = blockIdx.x; it < niter; it += gridDim.x) {
    int base = it * 32;
    if (base + 32 <= Q) {
      float4 v[4];
      int a[4];
#pragma unroll
      for (int i = 0; i < 4; ++i) {
        int row = base + i * 8 + r;
        v[i] = *(const float4*)&qe[(size_t)row * D + lane * 4];
        a[i] = assign[row] * D + lane;
      }
#pragma unroll
      for (int i = 0; i < 4; ++i) {
        atomicMax(&buf[a[i] +  0], f2key(v[i].x));
        atomicMax(&buf[a[i] + 32], f2key(v[i].y));
        atomicMax(&buf[a[i] + 64], f2key(v[i].z));
        atomicMax(&buf[a[i] + 96], f2key(v[i].w));
      }
    } else {
      for (int i = 0; i < 4; ++i) {
        int row = base + i * 8 + r;
        if (row < Q) {
          float4 v = *(const float4*)&qe[(size_t)row * D + lane * 4];
          int a = assign[row] * D + lane;
          atomicMax(&buf[a +  0], f2key(v.x));
          atomicMax(&buf[a + 32], f2key(v.y));
          atomicMax(&buf[a + 64], f2key(v.z));
          atomicMax(&buf[a + 96], f2key(v.w));
        }
      }
    }
  }
  __syncthreads();

  // Un-swizzle on write-out (coalesced global; one-shot LDS gather).
  unsigned* outp = part + (size_t)blockIdx.x * (C * D);
  for (int i = tid; i < C * D; i += P1_THREADS) {
    int d = i & 127;
    outp[i] = buf[(i & ~127) + (d & 3) * 32 + (d >> 2)];
  }
}

// Phase 2: reduce nb partial key-buffers -> core_embs (padding applied).
// Block = 64 consecutive outputs (256 B contiguous per wave-load) x 4 readers.
__global__ __launch_bounds__(256) void p2_merge(
    const unsigned* __restrict__ part, const float* __restrict__ padding,
    float* __restrict__ core_embs, int nb) {
  __shared__ unsigned red[256];
  int tid = threadIdx.x;
  int o_local = tid & 63;
  int rdr = tid >> 6;  // 0..3
  int o = blockIdx.x * 64 + o_local;
  unsigned m = 0u;
#pragma unroll 8
  for (int br = rdr; br < nb; br += 4)
    m = max(m, part[(size_t)br * (C * D) + o]);
  red[tid] = m;
  __syncthreads();
  if (tid < 64) {
    unsigned k = max(max(red[tid], red[tid + 64]),
                     max(red[tid + 128], red[tid + 192]));
    core_embs[o] = k ? key2f(k) : padding[o & (D - 1)];
  }
}

// Phase 3a: tmp = core_embs @ W_msg   [C,D] x [D,D]
__global__ __launch_bounds__(D) void p3a_gemm(
    const float* __restrict__ core_embs, const float* __restrict__ Wmsg,
    float* __restrict__ tmp) {
  __shared__ float xrow[D];
  int t = threadIdx.x;
  int j = blockIdx.x;
  xrow[t] = core_embs[j * D + t];
  __syncthreads();
  float acc = 0.f;
#pragma unroll 8
  for (int k = 0; k < D; ++k) acc += xrow[k] * Wmsg[k * D + t];
  tmp[j * D + t] = acc;
}

// Phase 3b: out = relu(core_embs @ W_self + core_con @ tmp + b)
__global__ __launch_bounds__(D) void p3b_out(
    const float* __restrict__ core_embs, const float* __restrict__ con,
    const float* __restrict__ tmp, const float* __restrict__ Wself,
    const float* __restrict__ b, float* __restrict__ out) {
  __shared__ float ce[D];
  __shared__ float cr[C];
  int t = threadIdx.x;
  int c = blockIdx.x;
  ce[t] = core_embs[c * D + t];
  if (t < C) cr[t] = con[c * C + t];
  __syncthreads();
  float acc = b[t];
#pragma unroll 8
  for (int k = 0; k < D; ++k) acc += ce[k] * Wself[k * D + t];
#pragma unroll 8
  for (int j = 0; j < C; ++j) acc += cr[j] * tmp[j * D + t];
  out[c * D + t] = fmaxf(acc, 0.f);
}

extern "C" void kernel_launch(void* const* d_in, const int* in_sizes, int n_in,
                              void* d_out, int out_size, void* d_ws, size_t ws_size,
                              hipStream_t stream) {
  const int* assign    = (const int*)d_in[0];
  const float* qe      = (const float*)d_in[1];
  const float* padding = (const float*)d_in[2];
  const float* con     = (const float*)d_in[3];
  const float* Wself   = (const float*)d_in[4];
  const float* Wmsg    = (const float*)d_in[5];
  const float* b       = (const float*)d_in[6];
  float* out = (float*)d_out;
  int Q = in_sizes[0];

  const size_t slot = (size_t)C * D;  // 8192 elems = 32 KB
  size_t avail = ws_size / 4;
  long nb_max = (long)((avail > 2 * slot ? avail - 2 * slot : slot) / slot);
  int nb = (int)(nb_max < P1_GRID ? nb_max : P1_GRID);
  if (nb < 1) nb = 1;

  unsigned* part   = (unsigned*)d_ws;
  float* core_embs = (float*)((unsigned*)d_ws + (size_t)nb * slot);
  float* tmp       = core_embs + slot;

  int niter = (Q + 31) / 32;

  hipLaunchKernelGGL(p1_segmax, dim3(nb), dim3(P1_THREADS), 0, stream,
                     assign, qe, part, Q, niter);
  hipLaunchKernelGGL(p2_merge, dim3((C * D) / 64), dim3(256), 0, stream,
                     part, padding, core_embs, nb);
  hipLaunchKernelGGL(p3a_gemm, dim3(C), dim3(D), 0, stream,
                     core_embs, Wmsg, tmp);
  hipLaunchKernelGGL(p3b_out, dim3(C), dim3(D), 0, stream,
                     core_embs, con, tmp, Wself, b, out);
}